// Round 2
// baseline (163.767 us; speedup 1.0000x reference)
//
#include <hip/hip_runtime.h>

// Point-transformer block, all fp32 (reference is jnp.float32 end-to-end).
// One block per group (B*G = 16384), 256 threads = one thread per (i,j)
// neighbor pair (n=16 x n=16). Weights are wave-uniform -> scalar loads.

__global__ __launch_bounds__(256) void pt_main(
    const float* __restrict__ data,     // (BG, 16, 3)
    const float* __restrict__ wqkv,     // (3, 9)
    const float* __restrict__ pw1,      // (3, 64)
    const float* __restrict__ pb1,      // (64)
    const float* __restrict__ pw2,      // (64, 3)
    const float* __restrict__ pb2,      // (3)
    const float* __restrict__ aw1,      // (3, 12)
    const float* __restrict__ ab1,      // (12)
    const float* __restrict__ aw2,      // (12, 3)
    const float* __restrict__ ab2,      // (3)
    const float* __restrict__ mw1,      // (48, 48)
    const float* __restrict__ mb1,      // (48)
    const float* __restrict__ mw2,      // (48, 48)
    const float* __restrict__ mb2,      // (48)
    const float* __restrict__ mw3,      // (48, 1)
    const float* __restrict__ mb3,      // (1)
    float* __restrict__ out)            // (BG)
{
    __shared__ float s_pos[48];
    __shared__ float s_q[48], s_k[48], s_v[48];
    __shared__ float s_sa[48], s_h1[48];

    const int g = blockIdx.x;
    const int t = threadIdx.x;

    // ---- phase 0: load the 16 points (48 floats) into LDS ----
    if (t < 48) s_pos[t] = data[g * 48 + t];
    __syncthreads();

    // ---- phase 1: qkv = x @ w_qkv (16 threads) ----
    if (t < 16) {
        const float x0 = s_pos[t*3+0], x1 = s_pos[t*3+1], x2 = s_pos[t*3+2];
        #pragma unroll
        for (int c = 0; c < 3; ++c) {
            s_q[t*3+c] = fmaf(x0, wqkv[0*9+c+0], fmaf(x1, wqkv[1*9+c+0], x2*wqkv[2*9+c+0]));
            s_k[t*3+c] = fmaf(x0, wqkv[0*9+c+3], fmaf(x1, wqkv[1*9+c+3], x2*wqkv[2*9+c+3]));
            s_v[t*3+c] = fmaf(x0, wqkv[0*9+c+6], fmaf(x1, wqkv[1*9+c+6], x2*wqkv[2*9+c+6]));
        }
    }
    __syncthreads();

    // ---- phase 2: per-pair work. i = query index, j = key index ----
    const int i = t >> 4, j = t & 15;

    const float r0 = s_pos[i*3+0] - s_pos[j*3+0];
    const float r1 = s_pos[i*3+1] - s_pos[j*3+1];
    const float r2 = s_pos[i*3+2] - s_pos[j*3+2];

    // pos-MLP: rel_emb = relu(rel_pos @ pw1 + pb1) @ pw2 + pb2
    float e0 = pb2[0], e1 = pb2[1], e2 = pb2[2];
    #pragma unroll
    for (int h = 0; h < 64; ++h) {
        float hh = fmaf(r0, pw1[h], fmaf(r1, pw1[64+h], fmaf(r2, pw1[128+h], pb1[h])));
        hh = fmaxf(hh, 0.0f);
        e0 = fmaf(hh, pw2[h*3+0], e0);
        e1 = fmaf(hh, pw2[h*3+1], e1);
        e2 = fmaf(hh, pw2[h*3+2], e2);
    }

    // v_ij = v[j] + rel_emb ; sim input = (q[i]-k[j]) + rel_emb
    const float vi0 = s_v[j*3+0] + e0, vi1 = s_v[j*3+1] + e1, vi2 = s_v[j*3+2] + e2;
    const float si0 = s_q[i*3+0] - s_k[j*3+0] + e0;
    const float si1 = s_q[i*3+1] - s_k[j*3+1] + e1;
    const float si2 = s_q[i*3+2] - s_k[j*3+2] + e2;

    // attn-MLP: sim = relu(s_in @ aw1 + ab1) @ aw2 + ab2
    float m0 = ab2[0], m1 = ab2[1], m2 = ab2[2];
    #pragma unroll
    for (int gg = 0; gg < 12; ++gg) {
        float hg = fmaf(si0, aw1[gg], fmaf(si1, aw1[12+gg], fmaf(si2, aw1[24+gg], ab1[gg])));
        hg = fmaxf(hg, 0.0f);
        m0 = fmaf(hg, aw2[gg*3+0], m0);
        m1 = fmaf(hg, aw2[gg*3+1], m1);
        m2 = fmaf(hg, aw2[gg*3+2], m2);
    }

    // ---- softmax over j (16 consecutive lanes share the same i) ----
    float x0 = m0, x1 = m1, x2 = m2;
    #pragma unroll
    for (int mk = 1; mk < 16; mk <<= 1) {
        x0 = fmaxf(x0, __shfl_xor(x0, mk));
        x1 = fmaxf(x1, __shfl_xor(x1, mk));
        x2 = fmaxf(x2, __shfl_xor(x2, mk));
    }
    float p0 = __expf(m0 - x0), p1 = __expf(m1 - x1), p2 = __expf(m2 - x2);

    float n0 = p0 * vi0, n1 = p1 * vi1, n2 = p2 * vi2;   // numerators
    float d0 = p0, d1 = p1, d2 = p2;                      // denominators
    #pragma unroll
    for (int mk = 1; mk < 16; mk <<= 1) {
        n0 += __shfl_xor(n0, mk);  d0 += __shfl_xor(d0, mk);
        n1 += __shfl_xor(n1, mk);  d1 += __shfl_xor(d1, mk);
        n2 += __shfl_xor(n2, mk);  d2 += __shfl_xor(d2, mk);
    }
    if (j == 0) {
        s_sa[i*3+0] = n0 / d0;
        s_sa[i*3+1] = n1 / d1;
        s_sa[i*3+2] = n2 / d2;
    }
    __syncthreads();

    // ---- phase 3: MLP 48 -> 48 -> 48 -> 1 ----
    if (t < 48) {
        float h1 = mb1[t];
        #pragma unroll
        for (int c = 0; c < 48; ++c) h1 = fmaf(s_sa[c], mw1[c*48+t], h1);
        s_h1[t] = fmaxf(h1, 0.0f);
    }
    __syncthreads();

    float fv = 0.0f;
    if (t < 48) {
        float h2 = mb2[t];
        #pragma unroll
        for (int c = 0; c < 48; ++c) h2 = fmaf(s_h1[c], mw2[c*48+t], h2);
        h2 = fmaxf(h2, 0.0f);
        fv = h2 * mw3[t];
    }
    // reduce the 48 partials inside wave 0 (lanes 48-63 contribute 0)
    if (t < 64) {
        #pragma unroll
        for (int mk = 1; mk < 64; mk <<= 1) fv += __shfl_xor(fv, mk);
        if (t == 0) out[g] = fv + mb3[0];
    }
}

extern "C" void kernel_launch(void* const* d_in, const int* in_sizes, int n_in,
                              void* d_out, int out_size, void* d_ws, size_t ws_size,
                              hipStream_t stream) {
    // inputs (all float32): 0 original_points (unused), 1 data, 2..16 weights
    const float* data = (const float*)d_in[1];
    const int groups = out_size;  // B*G = 16384, one scalar per group

    pt_main<<<groups, 256, 0, stream>>>(
        data,
        (const float*)d_in[2],  (const float*)d_in[3],  (const float*)d_in[4],
        (const float*)d_in[5],  (const float*)d_in[6],  (const float*)d_in[7],
        (const float*)d_in[8],  (const float*)d_in[9],  (const float*)d_in[10],
        (const float*)d_in[11], (const float*)d_in[12], (const float*)d_in[13],
        (const float*)d_in[14], (const float*)d_in[15], (const float*)d_in[16],
        (float*)d_out);
}

// Round 3
// 156.633 us; speedup vs baseline: 1.0455x; 1.0455x over previous
//
#include <hip/hip_runtime.h>

// Point-transformer block, fp32. One block per group (B*G = 16384),
// 256 threads = one thread per (i,j) neighbor pair (16x16).
//
// R2: pos-MLP layer-1 decomposed: (pos_i - pos_j)@W1 + b ==
//     (pos_i@W1 + b) - (pos_j@W1).  a1/a2 tables (16x64) built once per
//     group in LDS; per-pair inner loop drops 3 fma -> 1 sub per hidden.
//     LDS stride 68 dwords: 16B-aligned for ds_read_b128, bank stride 4
//     -> worst 2-way aliasing (free per m136).

#define ASTRIDE 68

__global__ __launch_bounds__(256) void pt_main(
    const float* __restrict__ data,     // (BG, 16, 3)
    const float* __restrict__ wqkv,     // (3, 9)
    const float* __restrict__ pw1,      // (3, 64)
    const float* __restrict__ pb1,      // (64)
    const float* __restrict__ pw2,      // (64, 3)
    const float* __restrict__ pb2,      // (3)
    const float* __restrict__ aw1,      // (3, 12)
    const float* __restrict__ ab1,      // (12)
    const float* __restrict__ aw2,      // (12, 3)
    const float* __restrict__ ab2,      // (3)
    const float* __restrict__ mw1,      // (48, 48)
    const float* __restrict__ mb1,      // (48)
    const float* __restrict__ mw2,      // (48, 48)
    const float* __restrict__ mb2,      // (48)
    const float* __restrict__ mw3,      // (48, 1)
    const float* __restrict__ mb3,      // (1)
    float* __restrict__ out)            // (BG)
{
    __shared__ float s_pos[48];
    __shared__ float s_q[48], s_k[48], s_v[48];
    __shared__ float s_sa[48], s_h1[48];
    __shared__ float a1[16 * ASTRIDE];   // pos_i @ W1 + b1
    __shared__ float a2[16 * ASTRIDE];   // pos_j @ W1

    const int g = blockIdx.x;
    const int t = threadIdx.x;

    // ---- phase 0: load the 16 points (48 floats) into LDS ----
    if (t < 48) s_pos[t] = data[g * 48 + t];
    __syncthreads();

    // ---- phase 1a: qkv (48 threads: section 0=q, 1=k, 2=v) ----
    if (t < 48) {
        const int sec = t >> 4, p = t & 15;
        const float x0 = s_pos[p*3+0], x1 = s_pos[p*3+1], x2 = s_pos[p*3+2];
        float* dst = (sec == 0) ? s_q : (sec == 1) ? s_k : s_v;
        #pragma unroll
        for (int c = 0; c < 3; ++c) {
            dst[p*3+c] = fmaf(x0, wqkv[0*9 + sec*3 + c],
                         fmaf(x1, wqkv[1*9 + sec*3 + c],
                         x2 * wqkv[2*9 + sec*3 + c]));
        }
    }

    // ---- phase 1b: a-tables. thread t -> point i = t>>4, h-chunk (t&15)*4 ----
    {
        const int i  = t >> 4;
        const int hc = (t & 15) << 2;
        const float x0 = s_pos[i*3+0], x1 = s_pos[i*3+1], x2 = s_pos[i*3+2];
        float4 va, vb;
        #pragma unroll
        for (int c = 0; c < 4; ++c) {
            const int h = hc + c;
            const float s = fmaf(x0, pw1[h], fmaf(x1, pw1[64+h], x2 * pw1[128+h]));
            (&vb.x)[c] = s;            // no bias (j side)
            (&va.x)[c] = s + pb1[h];   // with bias (i side)
        }
        *(float4*)&a1[i * ASTRIDE + hc] = va;
        *(float4*)&a2[i * ASTRIDE + hc] = vb;
    }
    __syncthreads();

    // ---- phase 2: per-pair work. i = query index, j = key index ----
    const int i = t >> 4, j = t & 15;

    // pos-MLP: e = relu(a1[i] - a2[j]) @ pw2 + pb2
    float e0 = pb2[0], e1 = pb2[1], e2 = pb2[2];
    #pragma unroll
    for (int c16 = 0; c16 < 16; ++c16) {
        const int h0 = c16 * 4;
        const float4 ai = *(const float4*)&a1[i * ASTRIDE + h0];
        const float4 aj = *(const float4*)&a2[j * ASTRIDE + h0];
        #pragma unroll
        for (int c = 0; c < 4; ++c) {
            const float hh = fmaxf((&ai.x)[c] - (&aj.x)[c], 0.0f);
            e0 = fmaf(hh, pw2[(h0+c)*3+0], e0);
            e1 = fmaf(hh, pw2[(h0+c)*3+1], e1);
            e2 = fmaf(hh, pw2[(h0+c)*3+2], e2);
        }
    }

    // v_ij = v[j] + rel_emb ; sim input = (q[i]-k[j]) + rel_emb
    const float vi0 = s_v[j*3+0] + e0, vi1 = s_v[j*3+1] + e1, vi2 = s_v[j*3+2] + e2;
    const float si0 = s_q[i*3+0] - s_k[j*3+0] + e0;
    const float si1 = s_q[i*3+1] - s_k[j*3+1] + e1;
    const float si2 = s_q[i*3+2] - s_k[j*3+2] + e2;

    // attn-MLP: sim = relu(s_in @ aw1 + ab1) @ aw2 + ab2
    float m0 = ab2[0], m1 = ab2[1], m2 = ab2[2];
    #pragma unroll
    for (int gg = 0; gg < 12; ++gg) {
        float hg = fmaf(si0, aw1[gg], fmaf(si1, aw1[12+gg], fmaf(si2, aw1[24+gg], ab1[gg])));
        hg = fmaxf(hg, 0.0f);
        m0 = fmaf(hg, aw2[gg*3+0], m0);
        m1 = fmaf(hg, aw2[gg*3+1], m1);
        m2 = fmaf(hg, aw2[gg*3+2], m2);
    }

    // ---- softmax over j (16 consecutive lanes share the same i) ----
    float x0 = m0, x1 = m1, x2 = m2;
    #pragma unroll
    for (int mk = 1; mk < 16; mk <<= 1) {
        x0 = fmaxf(x0, __shfl_xor(x0, mk));
        x1 = fmaxf(x1, __shfl_xor(x1, mk));
        x2 = fmaxf(x2, __shfl_xor(x2, mk));
    }
    float p0 = __expf(m0 - x0), p1 = __expf(m1 - x1), p2 = __expf(m2 - x2);

    float n0 = p0 * vi0, n1 = p1 * vi1, n2 = p2 * vi2;   // numerators
    float d0 = p0, d1 = p1, d2 = p2;                      // denominators
    #pragma unroll
    for (int mk = 1; mk < 16; mk <<= 1) {
        n0 += __shfl_xor(n0, mk);  d0 += __shfl_xor(d0, mk);
        n1 += __shfl_xor(n1, mk);  d1 += __shfl_xor(d1, mk);
        n2 += __shfl_xor(n2, mk);  d2 += __shfl_xor(d2, mk);
    }
    if (j == 0) {
        s_sa[i*3+0] = n0 / d0;
        s_sa[i*3+1] = n1 / d1;
        s_sa[i*3+2] = n2 / d2;
    }
    __syncthreads();

    // ---- phase 3: MLP 48 -> 48 -> 48 -> 1 ----
    if (t < 48) {
        float h1 = mb1[t];
        #pragma unroll
        for (int c = 0; c < 48; ++c) h1 = fmaf(s_sa[c], mw1[c*48+t], h1);
        s_h1[t] = fmaxf(h1, 0.0f);
    }
    __syncthreads();

    float fv = 0.0f;
    if (t < 48) {
        float h2 = mb2[t];
        #pragma unroll
        for (int c = 0; c < 48; ++c) h2 = fmaf(s_h1[c], mw2[c*48+t], h2);
        h2 = fmaxf(h2, 0.0f);
        fv = h2 * mw3[t];
    }
    // reduce the 48 partials inside wave 0 (lanes 48-63 contribute 0)
    if (t < 64) {
        #pragma unroll
        for (int mk = 1; mk < 64; mk <<= 1) fv += __shfl_xor(fv, mk);
        if (t == 0) out[g] = fv + mb3[0];
    }
}

extern "C" void kernel_launch(void* const* d_in, const int* in_sizes, int n_in,
                              void* d_out, int out_size, void* d_ws, size_t ws_size,
                              hipStream_t stream) {
    // inputs (all float32): 0 original_points (unused), 1 data, 2..16 weights
    const float* data = (const float*)d_in[1];
    const int groups = out_size;  // B*G = 16384, one scalar per group

    pt_main<<<groups, 256, 0, stream>>>(
        data,
        (const float*)d_in[2],  (const float*)d_in[3],  (const float*)d_in[4],
        (const float*)d_in[5],  (const float*)d_in[6],  (const float*)d_in[7],
        (const float*)d_in[8],  (const float*)d_in[9],  (const float*)d_in[10],
        (const float*)d_in[11], (const float*)d_in[12], (const float*)d_in[13],
        (const float*)d_in[14], (const float*)d_in[15], (const float*)d_in[16],
        (float*)d_out);
}